// Round 4
// 8138.522 us; speedup vs baseline: 1.0994x; 1.0994x over previous
//
#include <hip/hip_runtime.h>
#include <math.h>

typedef float vf4 __attribute__((ext_vector_type(4)));

// Problem dims (fixed by reference)
constexpr int T  = 512;
constexpr int BB = 64;    // batch
constexpr int II = 256;   // input
constexpr int HH = 512;   // hidden

// d_out layout (floats): out[B,T,H] | s[2,B,H] | h[2,B,H] | c[2,B,H]
constexpr int SOFF = BB * T * HH;          // 16777216
constexpr int HOFF = SOFF + 2 * BB * HH;
constexpr int COFF = HOFF + 2 * BB * HH;

// Workspace layout (float offsets). ~15.3 MB.
constexpr int WS_WC0 = 0;          // [512 j][768 k] vf4  (Wx0;Wh0 stacked)
constexpr int WS_WC1 = 1572864;    // [512 j][1024 k] vf4 (Wx1;Wh1 stacked)
constexpr int WS_BH0 = 3670016;    // [512] vf4
constexpr int WS_BH1 = 3672064;
constexpr int WS_HX0 = 3674112;    // mem exchange: [2 slot][8 g][512 j][8 b] f
constexpr int WS_HX1 = 3739648;    // h1  exchange: same layout
constexpr int WS_FLG = 3809280;    // stamps: [8 g][64] u32

// ---------------- MALL-coherent primitives: plain sc0 sc1 ops, no atomics ----
__device__ __forceinline__ void bypass_st(float* p, float v) {
  asm volatile("global_store_dword %0, %1, off sc0 sc1" :: "v"(p), "v"(v) : "memory");
}
__device__ __forceinline__ void bypass_st_u32(unsigned* p, unsigned v) {
  asm volatile("global_store_dword %0, %1, off sc0 sc1" :: "v"(p), "v"(v) : "memory");
}
__device__ __forceinline__ unsigned bypass_ldu(const unsigned* p) {
  unsigned r;
  asm volatile("global_load_dword %0, %1, off sc0 sc1\n\ts_waitcnt vmcnt(0)"
               : "=&v"(r) : "v"(p) : "memory");
  return r;
}
// two 16B loads, ONE wait (batched latency)
__device__ __forceinline__ void bypass_ld2x4(const vf4* p0, const vf4* p1, vf4& r0, vf4& r1) {
  asm volatile(
      "global_load_dwordx4 %0, %2, off sc0 sc1\n\t"
      "global_load_dwordx4 %1, %3, off sc0 sc1\n\t"
      "s_waitcnt vmcnt(0)"
      : "=&v"(r0), "=&v"(r1) : "v"(p0), "v"(p1) : "memory");
}
// RELEASE DRAIN: the compiler's pre-barrier waitcnt only covers memory ops it
// emitted itself — inline-asm stores are opaque to its accounting. Every wave
// must drain its own outstanding (asm) stores BEFORE s_barrier so that the
// post-barrier flag store truly happens-after all data stores (canonical CDNA
// drain-then-flag release). Without this, the flag can outrun the data at the
// MALL and a consumer loading immediately on flag-observation reads the stale
// previous slot -> spike flips (r8-r10 failure signature, absmax ~1.0).
__device__ __forceinline__ void release_drain() {
  asm volatile("s_waitcnt vmcnt(0)" ::: "memory");
}

__device__ __forceinline__ float sigf(float x) { return 1.0f / (1.0f + __expf(-x)); }
__device__ __forceinline__ float tanh_fast(float x) {
  return 1.0f - 2.0f / (1.0f + __expf(2.0f * x));
}

__device__ __forceinline__ float sxor(float v, int m) { return __shfl_xor(v, m, 64); }
__device__ __forceinline__ vf4 sxor4(vf4 v, int m) {
  vf4 r; r.x = sxor(v.x, m); r.y = sxor(v.y, m); r.z = sxor(v.z, m); r.w = sxor(v.w, m);
  return r;
}

// 3-bit bit-reversal (self-inverse): lane<->batch map for the split butterfly
__device__ __forceinline__ int rev3(int v) {
  return ((v & 1) << 2) | (v & 2) | ((v >> 2) & 1);
}

// Batch-splitting butterfly: in: acc[8] = partials for batches 0..7 over this
// lane's k-chunk. out: complete wave-sum vf4 for batch rev3(kl&7) (8 replicas).
__device__ __forceinline__ vf4 reduce8(const vf4* acc, int kl) {
  const int sel = kl & 1;
  vf4 n0[4];
#pragma unroll
  for (int i = 0; i < 4; ++i) {
    vf4 snd = sel ? acc[i] : acc[i + 4];
    vf4 kp  = sel ? acc[i + 4] : acc[i];
    n0[i] = kp + sxor4(snd, 1);
  }
  const int sel2 = (kl >> 1) & 1;
  vf4 n1[2];
#pragma unroll
  for (int i = 0; i < 2; ++i) {
    vf4 snd = sel2 ? n0[i] : n0[i + 2];
    vf4 kp  = sel2 ? n0[i + 2] : n0[i];
    n1[i] = kp + sxor4(snd, 2);
  }
  const int sel3 = (kl >> 2) & 1;
  vf4 snd = sel3 ? n1[0] : n1[1];
  vf4 kp  = sel3 ? n1[1] : n1[0];
  vf4 r = kp + sxor4(snd, 4);
  r += sxor4(r, 8);
  r += sxor4(r, 16);
  r += sxor4(r, 32);
  return r;
}

// ---------------- setup kernels ----------------
__global__ void pack_wc(const float* __restrict__ A, const float* __restrict__ B,
                        int Ka, int K, float* __restrict__ Wp) {
  const int j = blockIdx.x;
  for (int k = threadIdx.x; k < K; k += 256) {
    const float* src = (k < Ka) ? (A + (size_t)k * 2048) : (B + (size_t)(k - Ka) * 2048);
    vf4 v = {src[j], src[512 + j], src[1024 + j], src[1536 + j]};
    ((vf4*)Wp)[(size_t)j * K + k] = v;
  }
}

__global__ void pack_bias(const float* __restrict__ bh0, const float* __restrict__ bh1,
                          float* __restrict__ bh0p, float* __restrict__ bh1p) {
  const int i = blockIdx.x * blockDim.x + threadIdx.x;  // 4096
  if (i < 2048) {
    bh0p[i] = bh0[(i & 3) * 512 + (i >> 2)];
  } else {
    int q = i - 2048;
    bh1p[q] = bh1[(q & 3) * 512 + (q >> 2)];
  }
}

// ---------------- main persistent kernel ----------------
// Round 11 (= r10 + explicit release drain): latency restructure.
//  - spike exchange eliminated: spike == (mem > 0.5f), recomputed by consumers
//    from the mem floats already exchanged (bit-exact).
//  - exchange layout [g][j][b]: a wave's 8 rep0 stores form ONE 32B packet.
//  - each wave polls its 2 producers (2jo, 2jo+1) with 1 poll lane per
//    producer + s_sleep(1) backoff, then immediately issues those producers'
//    mem+h1 chunks -> discovery and staging-load latency overlap per-producer.
//  - x(t+1) prefetched into regs (cached load) before S1, written post-poll.
//  - NEW: release_drain() in every wave before S1 — explicit s_waitcnt
//    vmcnt(0) covering the inline-asm data stores (compiler barrier-drain does
//    not track asm stores). Flag post after S1 is now a sound release.
// Safety: block's 16 waves collectively poll ALL 32 group flags, so S2(t)
// implies every group block passed S1(t) (and thus drained its h-stores and
// finished its staging reads of t-1, which are inline-vmcnt(0)-drained)
// before any hx slot is overwritten at t+1 — 2-slot buffering is sufficient.
__global__ __launch_bounds__(1024, 1) void aslstm_main(
    const vf4* __restrict__ Wc0p, const vf4* __restrict__ Wc1p,
    const vf4* __restrict__ bh0p, const vf4* __restrict__ bh1p,
    const float* __restrict__ x,
    float* __restrict__ hx0, float* __restrict__ hx1,
    unsigned* __restrict__ flags,
    float* __restrict__ out) {
  const int wg  = blockIdx.x;
  const int xcd = wg & 7;
  const int a   = wg >> 3;
  const int g   = a & 7;
  const int s   = (a >> 3) * 8 + xcd;
  const int tid = threadIdx.x;
  const int jo  = tid >> 6;          // wave -> j column
  const int kl  = tid & 63;          // lane -> k chunk
  const int j   = s * 16 + jo;
  const int b_loc  = rev3(kl & 7);   // batch this lane finalizes (8 replicas)
  const int b_glob = g * 8 + b_loc;
  const bool rep0  = (kl < 8);       // replica 0 does the stores

  __shared__ float cat0[8][776];     // [b][ x(256) | h0(512) | pad ]
  __shared__ float cat1[8][1032];    // [b][ s0(512) | h1(512) | pad ]

  float c0 = 0.0f, c1 = 0.0f, sp = 0.0f;

  // producer this wave waits on + its load chunk within that producer's region
  const int pl = (jo << 1) | (kl >> 5);   // producer block 0..31 (per lane half)
  const int lc = kl & 31;                 // vf4 chunk 0..31 within producer
  const int js = pl * 16 + (lc >> 1);     // column this chunk carries
  const int b0 = (lc & 1) * 4;            // first batch of the chunk
  const int fo = g * 4096 + pl * 128 + lc * 4;  // float offset in hx[slot]
  const bool poller = ((kl & 31) == 0);   // 1 poll lane per producer per wave

  // ---- prologue: stage x(0); h0(-1)=0 directly in LDS ----
  if (tid < 512) {
    int bx = tid >> 6, kx = (tid & 63) * 4;
    *(vf4*)&cat0[bx][kx] = *(const vf4*)&x[(size_t)(g * 8 + bx) * (T * II) + kx];
  }
  {
    int bz = tid >> 7, kz = (tid & 127) * 4;
    *(vf4*)&cat0[bz][256 + kz] = vf4{0.0f, 0.0f, 0.0f, 0.0f};
  }
  __syncthreads();

  for (int t = 0; t < T; ++t) {
    // ---------- dot0: [x_t ; h0[t-1]] @ Wc0 (K=768), R=1 weight loads ----------
    vf4 acc[8];
#pragma unroll
    for (int b = 0; b < 8; ++b) acc[b] = vf4{0, 0, 0, 0};
    {
      const vf4* wr = Wc0p + (size_t)j * 768;
#pragma unroll
      for (int ig = 0; ig < 3; ++ig) {
        const int k0 = ig * 256 + kl * 4;
        vf4 w0 = wr[k0], w1 = wr[k0 + 1], w2 = wr[k0 + 2], w3 = wr[k0 + 3];
#pragma unroll
        for (int b = 0; b < 8; ++b) {
          vf4 av = *(const vf4*)&cat0[b][k0];
          acc[b] += av.x * w0; acc[b] += av.y * w1;
          acc[b] += av.z * w2; acc[b] += av.w * w3;
        }
      }
    }

    // ---------- in-wave reduce + finalize layer 0 (registers only) ----------
    {
      vf4 p = reduce8(acc, kl) + bh0p[j];
      float cn  = sigf(p.y) * c0 + sigf(p.x) * tanh_fast(p.z);
      float mem = sigf(p.w) * tanh_fast(cn);   // s*0.2*(1-s) == 0 for s in {0,1}
      float sn  = (mem > 0.5f) ? 1.0f : 0.0f;
      c0 = cn; sp = sn;
      if (rep0) {
        // [g][j][b] layout: 8 lanes -> one coalesced 32B packet per wave
        bypass_st(&hx0[(t & 1) * 32768 + g * 4096 + j * 8 + b_loc], mem);
        if (t == T - 1) {
          out[SOFF + b_glob * 512 + j] = sn;
          out[HOFF + b_glob * 512 + j] = mem;
          out[COFF + b_glob * 512 + j] = cn;
        }
      }
    }

    // x(t+1) prefetch into regs (plain cached load; drained at release_drain)
    vf4 xv = vf4{0, 0, 0, 0};
    if (tid < 512 && t < T - 1) {
      int bx = tid >> 6, kx = (tid & 63) * 4;
      xv = *(const vf4*)&x[(size_t)(g * 8 + bx) * (T * II) + (size_t)(t + 1) * II + kx];
    }

    release_drain();  // explicit vmcnt(0): asm data stores acked before barrier
    __syncthreads();  // S1 — all 16 waves drained => block's h0(t) stores visible
    if (tid == 0) bypass_st_u32(&flags[g * 64 + s], (unsigned)(t + 1));

    // ---------- per-wave poll of own producers + chunk loads + staging ----------
    {
      const unsigned tgt = (unsigned)(t + 1);
      const unsigned* fp = &flags[g * 64 + pl];
      for (;;) {
        unsigned v = tgt;
        if (poller) v = bypass_ldu(fp);
        if (__all((int)(v >= tgt))) break;
        __builtin_amdgcn_s_sleep(1);   // backoff: keep fabric clear for stores
      }
      const vf4* mp = (const vf4*)(hx0 + (t & 1) * 32768 + fo);        // mem(t)
      const vf4* hp = (const vf4*)(hx1 + ((t + 1) & 1) * 32768 + fo);  // h1(t-1)
      vf4 mv, hv;
      bypass_ld2x4(mp, hp, mv, hv);
      // scatter to LDS (2-way bank aliasing only — free)
      cat0[b0 + 0][256 + js] = mv.x;
      cat0[b0 + 1][256 + js] = mv.y;
      cat0[b0 + 2][256 + js] = mv.z;
      cat0[b0 + 3][256 + js] = mv.w;
      cat1[b0 + 0][js] = (mv.x > 0.5f) ? 1.0f : 0.0f;   // spike recompute
      cat1[b0 + 1][js] = (mv.y > 0.5f) ? 1.0f : 0.0f;
      cat1[b0 + 2][js] = (mv.z > 0.5f) ? 1.0f : 0.0f;
      cat1[b0 + 3][js] = (mv.w > 0.5f) ? 1.0f : 0.0f;
      cat1[b0 + 0][512 + js] = hv.x;
      cat1[b0 + 1][512 + js] = hv.y;
      cat1[b0 + 2][512 + js] = hv.z;
      cat1[b0 + 3][512 + js] = hv.w;
      if (tid < 512) {
        int bx = tid >> 6, kx = (tid & 63) * 4;
        *(vf4*)&cat0[bx][kx] = xv;
      }
    }
    __syncthreads();  // S2

    // ---------- dot1: [s0[t] ; h1[t-1]] @ Wc1 (K=1024), R=1 ----------
#pragma unroll
    for (int b = 0; b < 8; ++b) acc[b] = vf4{0, 0, 0, 0};
    {
      const vf4* wr = Wc1p + (size_t)j * 1024;
#pragma unroll
      for (int ig = 0; ig < 4; ++ig) {
        const int k0 = ig * 256 + kl * 4;
        vf4 w0 = wr[k0], w1 = wr[k0 + 1], w2 = wr[k0 + 2], w3 = wr[k0 + 3];
#pragma unroll
        for (int b = 0; b < 8; ++b) {
          vf4 av = *(const vf4*)&cat1[b][k0];
          acc[b] += av.x * w0; acc[b] += av.y * w1;
          acc[b] += av.z * w2; acc[b] += av.w * w3;
        }
      }
    }

    // ---------- in-wave reduce + finalize layer 1 (registers only) ----------
    {
      vf4 p = reduce8(acc, kl) + bh1p[j];
      float cn  = sigf(p.y) * c1 + sigf(p.x) * tanh_fast(p.z);
      float hn  = sigf(p.w) * tanh_fast(cn);
      float h1n = hn * 0.2f + sp;              // output neuron: h*decay + input(spike)
      c1 = cn;
      if (rep0) {
        bypass_st(&hx1[(t & 1) * 32768 + g * 4096 + j * 8 + b_loc], h1n);
        out[(size_t)b_glob * (T * HH) + (size_t)t * HH + j] = h1n;
        if (t == T - 1) {
          out[HOFF + 32768 + b_glob * 512 + j] = h1n;
          out[COFF + 32768 + b_glob * 512 + j] = cn;
        }
      }
    }
    // no sync needed here: next step's cat0/cat1 writes happen only after
    // S1(t+1) (all waves past their dot0 reads) — barrier chain orders them.
    // h1(t) stores are drained by next step's release_drain before flag t+2.
  }
}

// ---------------- launch ----------------
extern "C" void kernel_launch(void* const* d_in, const int* in_sizes, int n_in,
                              void* d_out, int out_size, void* d_ws, size_t ws_size,
                              hipStream_t stream) {
  const float* x   = (const float*)d_in[0];
  const float* Wx0 = (const float*)d_in[1];
  const float* Wh0 = (const float*)d_in[2];
  const float* bh0 = (const float*)d_in[3];
  const float* Wx1 = (const float*)d_in[4];
  const float* Wh1 = (const float*)d_in[5];
  const float* bh1 = (const float*)d_in[6];
  float* out = (float*)d_out;
  float* ws  = (float*)d_ws;

  float* Wc0p  = ws + WS_WC0;
  float* Wc1p  = ws + WS_WC1;
  float* bh0pf = ws + WS_BH0;
  float* bh1pf = ws + WS_BH1;
  float* hx0   = ws + WS_HX0;
  float* hx1   = ws + WS_HX1;
  unsigned* flags = (unsigned*)(ws + WS_FLG);

  // zero: h exchanges (both slots; hx1 slot1 read at t=0), stamps, s1 out section
  hipMemsetAsync(hx0, 0, 2 * 64 * 512 * sizeof(float), stream);
  hipMemsetAsync(hx1, 0, 2 * 64 * 512 * sizeof(float), stream);
  hipMemsetAsync(flags, 0, 512 * sizeof(unsigned), stream);
  hipMemsetAsync(out + SOFF + BB * HH, 0, BB * HH * sizeof(float), stream);

  pack_wc<<<dim3(512), dim3(256), 0, stream>>>(Wx0, Wh0, 256, 768, Wc0p);
  pack_wc<<<dim3(512), dim3(256), 0, stream>>>(Wx1, Wh1, 512, 1024, Wc1p);
  pack_bias<<<dim3(16), dim3(256), 0, stream>>>(bh0, bh1, bh0pf, bh1pf);

  aslstm_main<<<dim3(256), dim3(1024), 0, stream>>>(
      (const vf4*)Wc0p, (const vf4*)Wc1p, (const vf4*)bh0pf, (const vf4*)bh1pf,
      x, hx0, hx1, flags, out);
}

// Round 5
// 7854.729 us; speedup vs baseline: 1.1391x; 1.0361x over previous
//
#include <hip/hip_runtime.h>
#include <math.h>

typedef float vf4 __attribute__((ext_vector_type(4)));

// Problem dims (fixed by reference)
constexpr int T  = 512;
constexpr int BB = 64;    // batch
constexpr int II = 256;   // input
constexpr int HH = 512;   // hidden

// d_out layout (floats): out[B,T,H] | s[2,B,H] | h[2,B,H] | c[2,B,H]
constexpr int SOFF = BB * T * HH;          // 16777216
constexpr int HOFF = SOFF + 2 * BB * HH;
constexpr int COFF = HOFF + 2 * BB * HH;

// Workspace layout (float offsets). ~15.3 MB.
constexpr int WS_WC0 = 0;          // [512 j][768 k] vf4  (Wx0;Wh0 stacked)
constexpr int WS_WC1 = 1572864;    // [512 j][1024 k] vf4 (Wx1;Wh1 stacked)
constexpr int WS_BH0 = 3670016;    // [512] vf4
constexpr int WS_BH1 = 3672064;
constexpr int WS_HX0 = 3674112;    // mem exchange: [2 slot][8 g][512 j][8 b] f
constexpr int WS_HX1 = 3739648;    // h1  exchange: same layout
constexpr int WS_FLG = 3809280;    // stamps: [8 g][64] u32

// ---------------- cross-XCD-coherent primitives: DEVICE scope (sc1) ---------
// gfx950 scope encoding: {sc1,sc0} = 00 CU / 01 SE / 10 DEVICE / 11 SYSTEM.
// r11 used "sc0 sc1" = SYSTEM scope -> bypassed the MALL too: rocprof showed
// FETCH_SIZE ~8.7MB/step == exactly the exchange-load volume, i.e. every
// exchange RT went to HBM (~2x the latency, 4.4GB/dispatch wasted BW).
// Cross-XCD coherence only requires bypassing the per-XCD L2; the MALL is a
// shared memory-side cache, coherent by construction. "sc1" alone = device
// scope: L2-bypassing, MALL-allocating. Do NOT mix scopes on one address
// (device-scope dirty data in MALL is invisible to a MALL-bypassing load).
__device__ __forceinline__ void bypass_st(float* p, float v) {
  asm volatile("global_store_dword %0, %1, off sc1" :: "v"(p), "v"(v) : "memory");
}
__device__ __forceinline__ void bypass_st_u32(unsigned* p, unsigned v) {
  asm volatile("global_store_dword %0, %1, off sc1" :: "v"(p), "v"(v) : "memory");
}
__device__ __forceinline__ unsigned bypass_ldu(const unsigned* p) {
  unsigned r;
  asm volatile("global_load_dword %0, %1, off sc1\n\ts_waitcnt vmcnt(0)"
               : "=&v"(r) : "v"(p) : "memory");
  return r;
}
// two 16B loads, ONE wait (batched latency)
__device__ __forceinline__ void bypass_ld2x4(const vf4* p0, const vf4* p1, vf4& r0, vf4& r1) {
  asm volatile(
      "global_load_dwordx4 %0, %2, off sc1\n\t"
      "global_load_dwordx4 %1, %3, off sc1\n\t"
      "s_waitcnt vmcnt(0)"
      : "=&v"(r0), "=&v"(r1) : "v"(p0), "v"(p1) : "memory");
}
// RELEASE DRAIN: the compiler's pre-barrier waitcnt only covers memory ops it
// emitted itself — inline-asm stores are opaque to its accounting. Every wave
// must drain its own outstanding (asm) stores BEFORE s_barrier so that the
// post-barrier flag store truly happens-after all data stores (canonical CDNA
// drain-then-flag release). Without this, the flag can outrun the data and a
// consumer loading immediately on flag-observation reads the stale previous
// slot -> spike flips (r8-r10 failure signature, absmax ~1.0).
__device__ __forceinline__ void release_drain() {
  asm volatile("s_waitcnt vmcnt(0)" ::: "memory");
}

__device__ __forceinline__ float sigf(float x) { return 1.0f / (1.0f + __expf(-x)); }
__device__ __forceinline__ float tanh_fast(float x) {
  return 1.0f - 2.0f / (1.0f + __expf(2.0f * x));
}

__device__ __forceinline__ float sxor(float v, int m) { return __shfl_xor(v, m, 64); }
__device__ __forceinline__ vf4 sxor4(vf4 v, int m) {
  vf4 r; r.x = sxor(v.x, m); r.y = sxor(v.y, m); r.z = sxor(v.z, m); r.w = sxor(v.w, m);
  return r;
}

// 3-bit bit-reversal (self-inverse): lane<->batch map for the split butterfly
__device__ __forceinline__ int rev3(int v) {
  return ((v & 1) << 2) | (v & 2) | ((v >> 2) & 1);
}

// Batch-splitting butterfly: in: acc[8] = partials for batches 0..7 over this
// lane's k-chunk. out: complete wave-sum vf4 for batch rev3(kl&7) (8 replicas).
__device__ __forceinline__ vf4 reduce8(const vf4* acc, int kl) {
  const int sel = kl & 1;
  vf4 n0[4];
#pragma unroll
  for (int i = 0; i < 4; ++i) {
    vf4 snd = sel ? acc[i] : acc[i + 4];
    vf4 kp  = sel ? acc[i + 4] : acc[i];
    n0[i] = kp + sxor4(snd, 1);
  }
  const int sel2 = (kl >> 1) & 1;
  vf4 n1[2];
#pragma unroll
  for (int i = 0; i < 2; ++i) {
    vf4 snd = sel2 ? n0[i] : n0[i + 2];
    vf4 kp  = sel2 ? n0[i + 2] : n0[i];
    n1[i] = kp + sxor4(snd, 2);
  }
  const int sel3 = (kl >> 2) & 1;
  vf4 snd = sel3 ? n1[0] : n1[1];
  vf4 kp  = sel3 ? n1[1] : n1[0];
  vf4 r = kp + sxor4(snd, 4);
  r += sxor4(r, 8);
  r += sxor4(r, 16);
  r += sxor4(r, 32);
  return r;
}

// ---------------- setup kernels ----------------
__global__ void pack_wc(const float* __restrict__ A, const float* __restrict__ B,
                        int Ka, int K, float* __restrict__ Wp) {
  const int j = blockIdx.x;
  for (int k = threadIdx.x; k < K; k += 256) {
    const float* src = (k < Ka) ? (A + (size_t)k * 2048) : (B + (size_t)(k - Ka) * 2048);
    vf4 v = {src[j], src[512 + j], src[1024 + j], src[1536 + j]};
    ((vf4*)Wp)[(size_t)j * K + k] = v;
  }
}

__global__ void pack_bias(const float* __restrict__ bh0, const float* __restrict__ bh1,
                          float* __restrict__ bh0p, float* __restrict__ bh1p) {
  const int i = blockIdx.x * blockDim.x + threadIdx.x;  // 4096
  if (i < 2048) {
    bh0p[i] = bh0[(i & 3) * 512 + (i >> 2)];
  } else {
    int q = i - 2048;
    bh1p[q] = bh1[(q & 3) * 512 + (q >> 2)];
  }
}

// ---------------- main persistent kernel ----------------
// Round 12 (= r11 passing kernel + device-scope exchange). Structure:
//  - spike exchange eliminated: spike == (mem > 0.5f), recomputed by consumers
//    from the mem floats already exchanged (bit-exact).
//  - exchange layout [g][j][b]: a wave's 8 rep0 stores form ONE 32B packet.
//  - each wave polls its 2 producers (2jo, 2jo+1) with 1 poll lane per
//    producer + s_sleep(1) backoff, then immediately issues those producers'
//    mem+h1 chunks -> discovery and staging-load latency overlap per-producer.
//  - x(t+1) prefetched into regs (cached load) before S1, written post-poll.
//  - release_drain() in every wave before S1 (r11 fix, load-bearing).
//  - NEW (this round): exchange ops at DEVICE scope (sc1) instead of SYSTEM
//    (sc0 sc1) -> MALL-resident exchange, ~half the RT latency, no HBM traffic.
// Safety: block's 16 waves collectively poll ALL 32 group flags, so S2(t)
// implies every group block passed S1(t) (and thus drained its h-stores and
// finished its staging reads of t-1, which are inline-vmcnt(0)-drained)
// before any hx slot is overwritten at t+1 — 2-slot buffering is sufficient.
__global__ __launch_bounds__(1024, 1) void aslstm_main(
    const vf4* __restrict__ Wc0p, const vf4* __restrict__ Wc1p,
    const vf4* __restrict__ bh0p, const vf4* __restrict__ bh1p,
    const float* __restrict__ x,
    float* __restrict__ hx0, float* __restrict__ hx1,
    unsigned* __restrict__ flags,
    float* __restrict__ out) {
  const int wg  = blockIdx.x;
  const int xcd = wg & 7;
  const int a   = wg >> 3;
  const int g   = a & 7;
  const int s   = (a >> 3) * 8 + xcd;
  const int tid = threadIdx.x;
  const int jo  = tid >> 6;          // wave -> j column
  const int kl  = tid & 63;          // lane -> k chunk
  const int j   = s * 16 + jo;
  const int b_loc  = rev3(kl & 7);   // batch this lane finalizes (8 replicas)
  const int b_glob = g * 8 + b_loc;
  const bool rep0  = (kl < 8);       // replica 0 does the stores

  __shared__ float cat0[8][776];     // [b][ x(256) | h0(512) | pad ]
  __shared__ float cat1[8][1032];    // [b][ s0(512) | h1(512) | pad ]

  float c0 = 0.0f, c1 = 0.0f, sp = 0.0f;

  // producer this wave waits on + its load chunk within that producer's region
  const int pl = (jo << 1) | (kl >> 5);   // producer block 0..31 (per lane half)
  const int lc = kl & 31;                 // vf4 chunk 0..31 within producer
  const int js = pl * 16 + (lc >> 1);     // column this chunk carries
  const int b0 = (lc & 1) * 4;            // first batch of the chunk
  const int fo = g * 4096 + pl * 128 + lc * 4;  // float offset in hx[slot]
  const bool poller = ((kl & 31) == 0);   // 1 poll lane per producer per wave

  // ---- prologue: stage x(0); h0(-1)=0 directly in LDS ----
  if (tid < 512) {
    int bx = tid >> 6, kx = (tid & 63) * 4;
    *(vf4*)&cat0[bx][kx] = *(const vf4*)&x[(size_t)(g * 8 + bx) * (T * II) + kx];
  }
  {
    int bz = tid >> 7, kz = (tid & 127) * 4;
    *(vf4*)&cat0[bz][256 + kz] = vf4{0.0f, 0.0f, 0.0f, 0.0f};
  }
  __syncthreads();

  for (int t = 0; t < T; ++t) {
    // ---------- dot0: [x_t ; h0[t-1]] @ Wc0 (K=768), R=1 weight loads ----------
    vf4 acc[8];
#pragma unroll
    for (int b = 0; b < 8; ++b) acc[b] = vf4{0, 0, 0, 0};
    {
      const vf4* wr = Wc0p + (size_t)j * 768;
#pragma unroll
      for (int ig = 0; ig < 3; ++ig) {
        const int k0 = ig * 256 + kl * 4;
        vf4 w0 = wr[k0], w1 = wr[k0 + 1], w2 = wr[k0 + 2], w3 = wr[k0 + 3];
#pragma unroll
        for (int b = 0; b < 8; ++b) {
          vf4 av = *(const vf4*)&cat0[b][k0];
          acc[b] += av.x * w0; acc[b] += av.y * w1;
          acc[b] += av.z * w2; acc[b] += av.w * w3;
        }
      }
    }

    // ---------- in-wave reduce + finalize layer 0 (registers only) ----------
    {
      vf4 p = reduce8(acc, kl) + bh0p[j];
      float cn  = sigf(p.y) * c0 + sigf(p.x) * tanh_fast(p.z);
      float mem = sigf(p.w) * tanh_fast(cn);   // s*0.2*(1-s) == 0 for s in {0,1}
      float sn  = (mem > 0.5f) ? 1.0f : 0.0f;
      c0 = cn; sp = sn;
      if (rep0) {
        // [g][j][b] layout: 8 lanes -> one coalesced 32B packet per wave
        bypass_st(&hx0[(t & 1) * 32768 + g * 4096 + j * 8 + b_loc], mem);
        if (t == T - 1) {
          out[SOFF + b_glob * 512 + j] = sn;
          out[HOFF + b_glob * 512 + j] = mem;
          out[COFF + b_glob * 512 + j] = cn;
        }
      }
    }

    // x(t+1) prefetch into regs (plain cached load; drained at release_drain)
    vf4 xv = vf4{0, 0, 0, 0};
    if (tid < 512 && t < T - 1) {
      int bx = tid >> 6, kx = (tid & 63) * 4;
      xv = *(const vf4*)&x[(size_t)(g * 8 + bx) * (T * II) + (size_t)(t + 1) * II + kx];
    }

    release_drain();  // explicit vmcnt(0): asm data stores acked before barrier
    __syncthreads();  // S1 — all 16 waves drained => block's h0(t) stores visible
    if (tid == 0) bypass_st_u32(&flags[g * 64 + s], (unsigned)(t + 1));

    // ---------- per-wave poll of own producers + chunk loads + staging ----------
    {
      const unsigned tgt = (unsigned)(t + 1);
      const unsigned* fp = &flags[g * 64 + pl];
      for (;;) {
        unsigned v = tgt;
        if (poller) v = bypass_ldu(fp);
        if (__all((int)(v >= tgt))) break;
        __builtin_amdgcn_s_sleep(1);   // backoff: keep fabric clear for stores
      }
      const vf4* mp = (const vf4*)(hx0 + (t & 1) * 32768 + fo);        // mem(t)
      const vf4* hp = (const vf4*)(hx1 + ((t + 1) & 1) * 32768 + fo);  // h1(t-1)
      vf4 mv, hv;
      bypass_ld2x4(mp, hp, mv, hv);
      // scatter to LDS (2-way bank aliasing only — free)
      cat0[b0 + 0][256 + js] = mv.x;
      cat0[b0 + 1][256 + js] = mv.y;
      cat0[b0 + 2][256 + js] = mv.z;
      cat0[b0 + 3][256 + js] = mv.w;
      cat1[b0 + 0][js] = (mv.x > 0.5f) ? 1.0f : 0.0f;   // spike recompute
      cat1[b0 + 1][js] = (mv.y > 0.5f) ? 1.0f : 0.0f;
      cat1[b0 + 2][js] = (mv.z > 0.5f) ? 1.0f : 0.0f;
      cat1[b0 + 3][js] = (mv.w > 0.5f) ? 1.0f : 0.0f;
      cat1[b0 + 0][512 + js] = hv.x;
      cat1[b0 + 1][512 + js] = hv.y;
      cat1[b0 + 2][512 + js] = hv.z;
      cat1[b0 + 3][512 + js] = hv.w;
      if (tid < 512) {
        int bx = tid >> 6, kx = (tid & 63) * 4;
        *(vf4*)&cat0[bx][kx] = xv;
      }
    }
    __syncthreads();  // S2

    // ---------- dot1: [s0[t] ; h1[t-1]] @ Wc1 (K=1024), R=1 ----------
#pragma unroll
    for (int b = 0; b < 8; ++b) acc[b] = vf4{0, 0, 0, 0};
    {
      const vf4* wr = Wc1p + (size_t)j * 1024;
#pragma unroll
      for (int ig = 0; ig < 4; ++ig) {
        const int k0 = ig * 256 + kl * 4;
        vf4 w0 = wr[k0], w1 = wr[k0 + 1], w2 = wr[k0 + 2], w3 = wr[k0 + 3];
#pragma unroll
        for (int b = 0; b < 8; ++b) {
          vf4 av = *(const vf4*)&cat1[b][k0];
          acc[b] += av.x * w0; acc[b] += av.y * w1;
          acc[b] += av.z * w2; acc[b] += av.w * w3;
        }
      }
    }

    // ---------- in-wave reduce + finalize layer 1 (registers only) ----------
    {
      vf4 p = reduce8(acc, kl) + bh1p[j];
      float cn  = sigf(p.y) * c1 + sigf(p.x) * tanh_fast(p.z);
      float hn  = sigf(p.w) * tanh_fast(cn);
      float h1n = hn * 0.2f + sp;              // output neuron: h*decay + input(spike)
      c1 = cn;
      if (rep0) {
        bypass_st(&hx1[(t & 1) * 32768 + g * 4096 + j * 8 + b_loc], h1n);
        out[(size_t)b_glob * (T * HH) + (size_t)t * HH + j] = h1n;
        if (t == T - 1) {
          out[HOFF + 32768 + b_glob * 512 + j] = h1n;
          out[COFF + 32768 + b_glob * 512 + j] = cn;
        }
      }
    }
    // no sync needed here: next step's cat0/cat1 writes happen only after
    // S1(t+1) (all waves past their dot0 reads) — barrier chain orders them.
    // h1(t) stores are drained by next step's release_drain before flag t+2.
  }
}

// ---------------- launch ----------------
extern "C" void kernel_launch(void* const* d_in, const int* in_sizes, int n_in,
                              void* d_out, int out_size, void* d_ws, size_t ws_size,
                              hipStream_t stream) {
  const float* x   = (const float*)d_in[0];
  const float* Wx0 = (const float*)d_in[1];
  const float* Wh0 = (const float*)d_in[2];
  const float* bh0 = (const float*)d_in[3];
  const float* Wx1 = (const float*)d_in[4];
  const float* Wh1 = (const float*)d_in[5];
  const float* bh1 = (const float*)d_in[6];
  float* out = (float*)d_out;
  float* ws  = (float*)d_ws;

  float* Wc0p  = ws + WS_WC0;
  float* Wc1p  = ws + WS_WC1;
  float* bh0pf = ws + WS_BH0;
  float* bh1pf = ws + WS_BH1;
  float* hx0   = ws + WS_HX0;
  float* hx1   = ws + WS_HX1;
  unsigned* flags = (unsigned*)(ws + WS_FLG);

  // zero: h exchanges (both slots; hx1 slot1 read at t=0), stamps, s1 out section
  hipMemsetAsync(hx0, 0, 2 * 64 * 512 * sizeof(float), stream);
  hipMemsetAsync(hx1, 0, 2 * 64 * 512 * sizeof(float), stream);
  hipMemsetAsync(flags, 0, 512 * sizeof(unsigned), stream);
  hipMemsetAsync(out + SOFF + BB * HH, 0, BB * HH * sizeof(float), stream);

  pack_wc<<<dim3(512), dim3(256), 0, stream>>>(Wx0, Wh0, 256, 768, Wc0p);
  pack_wc<<<dim3(512), dim3(256), 0, stream>>>(Wx1, Wh1, 512, 1024, Wc1p);
  pack_bias<<<dim3(16), dim3(256), 0, stream>>>(bh0, bh1, bh0pf, bh1pf);

  aslstm_main<<<dim3(256), dim3(1024), 0, stream>>>(
      (const vf4*)Wc0p, (const vf4*)Wc1p, (const vf4*)bh0pf, (const vf4*)bh1pf,
      x, hx0, hx1, flags, out);
}

// Round 6
// 7677.016 us; speedup vs baseline: 1.1654x; 1.0231x over previous
//
#include <hip/hip_runtime.h>
#include <math.h>

typedef float vf4 __attribute__((ext_vector_type(4)));

// Problem dims (fixed by reference)
constexpr int T  = 512;
constexpr int BB = 64;    // batch
constexpr int II = 256;   // input
constexpr int HH = 512;   // hidden

// d_out layout (floats): out[B,T,H] | s[2,B,H] | h[2,B,H] | c[2,B,H]
constexpr int SOFF = BB * T * HH;          // 16777216
constexpr int HOFF = SOFF + 2 * BB * HH;
constexpr int COFF = HOFF + 2 * BB * HH;

// Workspace layout (float offsets). ~15.3 MB.
constexpr int WS_WC0 = 0;          // [512 j][768 k] vf4  (Wx0;Wh0 stacked)
constexpr int WS_WC1 = 1572864;    // [512 j][1024 k] vf4 (Wx1;Wh1 stacked)
constexpr int WS_BH0 = 3670016;    // [512] vf4
constexpr int WS_BH1 = 3672064;
constexpr int WS_HX0 = 3674112;    // mem exchange: [2 slot][8 g][512 j][8 b] f
constexpr int WS_HX1 = 3739648;    // h1  exchange: same layout

// ---------------- cross-XCD-coherent primitives: DEVICE scope (sc1) ---------
// sc1 = device scope: bypasses the (incoherent) per-XCD L2, MALL-resident.
// r12 lesson: FETCH_SIZE counts TCC<->fabric traffic; MALL hits are behind it.
__device__ __forceinline__ void bypass_st(float* p, float v) {
  asm volatile("global_store_dword %0, %1, off sc1" :: "v"(p), "v"(v) : "memory");
}
// two 16B loads, ONE wait (batched latency); "=&v" early-clobber load-bearing
__device__ __forceinline__ void bypass_ld2x4(const vf4* p0, const vf4* p1, vf4& r0, vf4& r1) {
  asm volatile(
      "global_load_dwordx4 %0, %2, off sc1\n\t"
      "global_load_dwordx4 %1, %3, off sc1\n\t"
      "s_waitcnt vmcnt(0)"
      : "=&v"(r0), "=&v"(r1) : "v"(p0), "v"(p1) : "memory");
}

// ---------------- self-validating tagged exchange ----------------
// Values exchanged are bounded: mem in (-1,1), h1 in (-0.2,1.2). Producer at
// step t stores  v' = v + OFF(t),  OFF(t) = 4 + 4*((t>>1)&1)  -> bands
// (3,5.2) for tag0, (7,9.2) for tag1. A slot is revisited at t+2, whose tag
// always FLIPS ((t+2)>>1 flips bit 0), and memset zeros match neither band —
// so band membership == "this step's value is here". The tag travels IN the
// same atomic dword as the data: no flags, no release drain, no S1 barrier.
// Decode error of the add/sub round trip <= 2^-20*8 ~ 1e-5, vastly below the
// 2e-3 spike-threshold margin the data has (r11/r12 passed with absmax 2e-3)
// and the 0.032 check threshold.
__device__ __forceinline__ bool tag_ok(float v, bool hi) {
  return hi ? (v > 6.0f) : (v > 2.0f && v < 6.0f);
}

__device__ __forceinline__ float sigf(float x) { return 1.0f / (1.0f + __expf(-x)); }
__device__ __forceinline__ float tanh_fast(float x) {
  return 1.0f - 2.0f / (1.0f + __expf(2.0f * x));
}

__device__ __forceinline__ float sxor(float v, int m) { return __shfl_xor(v, m, 64); }
__device__ __forceinline__ vf4 sxor4(vf4 v, int m) {
  vf4 r; r.x = sxor(v.x, m); r.y = sxor(v.y, m); r.z = sxor(v.z, m); r.w = sxor(v.w, m);
  return r;
}

// 3-bit bit-reversal (self-inverse): lane<->batch map for the split butterfly
__device__ __forceinline__ int rev3(int v) {
  return ((v & 1) << 2) | (v & 2) | ((v >> 2) & 1);
}

// Batch-splitting butterfly: in: acc[8] = partials for batches 0..7 over this
// lane's k-chunk. out: complete wave-sum vf4 for batch rev3(kl&7) (8 replicas).
__device__ __forceinline__ vf4 reduce8(const vf4* acc, int kl) {
  const int sel = kl & 1;
  vf4 n0[4];
#pragma unroll
  for (int i = 0; i < 4; ++i) {
    vf4 snd = sel ? acc[i] : acc[i + 4];
    vf4 kp  = sel ? acc[i + 4] : acc[i];
    n0[i] = kp + sxor4(snd, 1);
  }
  const int sel2 = (kl >> 1) & 1;
  vf4 n1[2];
#pragma unroll
  for (int i = 0; i < 2; ++i) {
    vf4 snd = sel2 ? n0[i] : n0[i + 2];
    vf4 kp  = sel2 ? n0[i + 2] : n0[i];
    n1[i] = kp + sxor4(snd, 2);
  }
  const int sel3 = (kl >> 2) & 1;
  vf4 snd = sel3 ? n1[0] : n1[1];
  vf4 kp  = sel3 ? n1[1] : n1[0];
  vf4 r = kp + sxor4(snd, 4);
  r += sxor4(r, 8);
  r += sxor4(r, 16);
  r += sxor4(r, 32);
  return r;
}

// ---------------- setup kernels ----------------
__global__ void pack_wc(const float* __restrict__ A, const float* __restrict__ B,
                        int Ka, int K, float* __restrict__ Wp) {
  const int j = blockIdx.x;
  for (int k = threadIdx.x; k < K; k += 256) {
    const float* src = (k < Ka) ? (A + (size_t)k * 2048) : (B + (size_t)(k - Ka) * 2048);
    vf4 v = {src[j], src[512 + j], src[1024 + j], src[1536 + j]};
    ((vf4*)Wp)[(size_t)j * K + k] = v;
  }
}

__global__ void pack_bias(const float* __restrict__ bh0, const float* __restrict__ bh1,
                          float* __restrict__ bh0p, float* __restrict__ bh1p) {
  const int i = blockIdx.x * blockDim.x + threadIdx.x;  // 4096
  if (i < 2048) {
    bh0p[i] = bh0[(i & 3) * 512 + (i >> 2)];
  } else {
    int q = i - 2048;
    bh1p[q] = bh1[(q & 3) * 512 + (q >> 2)];
  }
}

// hx1 slot1 must read as "h1(-1)=0 with tag1" at t=0: fill with 0 + 8.0.
__global__ void fill_tag(float* __restrict__ p, float v) {
  p[blockIdx.x * 1024 + threadIdx.x] = v;
}

// ---------------- main persistent kernel ----------------
// Round 13: self-validating tagged exchange, ONE barrier per step.
//  - No flags, no release drain, no S1: the band-tag travels in the data
//    dword itself (atomic), so a band-valid load IS the acquire.
//  - cat0 AND cat1 double-buffered (113 KB LDS): scatter(t) writes
//    cat0[(t+1)&1]/cat1[t&1] while laggard waves may still read
//    cat0[t&1] (dot0) or cat1[(t-1)&1] (dot1) — all disjoint. The single
//    S2 orders scatter(t) vs dot1(t) reads; barrier-iteration skew is
//    impossible with one barrier per loop.
//  - Slot-overwrite safety (no S1): X stores slot(t) only after X *loaded*
//    band-valid t-1 data from every producer P, which happens-after P's
//    t-2 staging reads completed (program order + inline vmcnt drain on
//    the staging loads). 2-slot ring remains sound with zero inter-block
//    barriers.
//  - Poll = retry the SAME ld2x4 that fetches the data (productive poll,
//    no separate flag RT, no sleep).
__global__ __launch_bounds__(1024, 1) void aslstm_main(
    const vf4* __restrict__ Wc0p, const vf4* __restrict__ Wc1p,
    const vf4* __restrict__ bh0p, const vf4* __restrict__ bh1p,
    const float* __restrict__ x,
    float* __restrict__ hx0, float* __restrict__ hx1,
    float* __restrict__ out) {
  const int wg  = blockIdx.x;
  const int xcd = wg & 7;
  const int a   = wg >> 3;
  const int g   = a & 7;
  const int s   = (a >> 3) * 8 + xcd;
  const int tid = threadIdx.x;
  const int jo  = tid >> 6;          // wave -> j column
  const int kl  = tid & 63;          // lane -> k chunk
  const int j   = s * 16 + jo;
  const int b_loc  = rev3(kl & 7);   // batch this lane finalizes (8 replicas)
  const int b_glob = g * 8 + b_loc;
  const bool rep0  = (kl < 8);       // replica 0 does the stores

  __shared__ float cat0[2][8][776];   // [buf][b][ x(256) | h0(512) | pad ]
  __shared__ float cat1[2][8][1032];  // [buf][b][ s0(512) | h1(512) | pad ]

  float c0 = 0.0f, c1 = 0.0f, sp = 0.0f;

  // producer this wave waits on + its load chunk within that producer's region
  const int pl = (jo << 1) | (kl >> 5);   // producer block 0..31 (per lane half)
  const int lc = kl & 31;                 // vf4 chunk 0..31 within producer
  const int js = pl * 16 + (lc >> 1);     // column this chunk carries
  const int b0 = (lc & 1) * 4;            // first batch of the chunk
  const int fo = g * 4096 + pl * 128 + lc * 4;  // float offset in hx[slot]

  // ---- prologue: stage x(0); h0(-1)=0 directly in LDS buf0 ----
  if (tid < 512) {
    int bx = tid >> 6, kx = (tid & 63) * 4;
    *(vf4*)&cat0[0][bx][kx] = *(const vf4*)&x[(size_t)(g * 8 + bx) * (T * II) + kx];
  }
  {
    int bz = tid >> 7, kz = (tid & 127) * 4;
    *(vf4*)&cat0[0][bz][256 + kz] = vf4{0.0f, 0.0f, 0.0f, 0.0f};
  }
  __syncthreads();

  for (int t = 0; t < T; ++t) {
    const int p0 = t & 1, p1 = p0 ^ 1;
    const bool tagm = ((t >> 1) & 1) != 0;        // band of step-t values
    const bool tagh = (((t + 3) >> 1) & 1) != 0;  // band of step-(t-1) values
    const float offm = tagm ? 8.0f : 4.0f;
    const float offh = tagh ? 8.0f : 4.0f;

    // ---------- dot0: [x_t ; h0[t-1]] @ Wc0 (K=768), R=1 weight loads ----------
    vf4 acc[8];
#pragma unroll
    for (int b = 0; b < 8; ++b) acc[b] = vf4{0, 0, 0, 0};
    {
      const vf4* wr = Wc0p + (size_t)j * 768;
#pragma unroll
      for (int ig = 0; ig < 3; ++ig) {
        const int k0 = ig * 256 + kl * 4;
        vf4 w0 = wr[k0], w1 = wr[k0 + 1], w2 = wr[k0 + 2], w3 = wr[k0 + 3];
#pragma unroll
        for (int b = 0; b < 8; ++b) {
          vf4 av = *(const vf4*)&cat0[p0][b][k0];
          acc[b] += av.x * w0; acc[b] += av.y * w1;
          acc[b] += av.z * w2; acc[b] += av.w * w3;
        }
      }
    }

    // ---------- in-wave reduce + finalize layer 0 (registers only) ----------
    {
      vf4 p = reduce8(acc, kl) + bh0p[j];
      float cn  = sigf(p.y) * c0 + sigf(p.x) * tanh_fast(p.z);
      float mem = sigf(p.w) * tanh_fast(cn);   // s*0.2*(1-s) == 0 for s in {0,1}
      float sn  = (mem > 0.5f) ? 1.0f : 0.0f;
      c0 = cn; sp = sn;
      if (rep0) {
        // tagged store: value + band offset, one coalesced 32B packet per wave
        bypass_st(&hx0[p0 * 32768 + g * 4096 + j * 8 + b_loc], mem + offm);
        if (t == T - 1) {
          out[SOFF + b_glob * 512 + j] = sn;
          out[HOFF + b_glob * 512 + j] = mem;
          out[COFF + b_glob * 512 + j] = cn;
        }
      }
    }

    // x(t+1) prefetch into regs (plain cached load)
    vf4 xv = vf4{0, 0, 0, 0};
    if (tid < 512 && t < T - 1) {
      int bx = tid >> 6, kx = (tid & 63) * 4;
      xv = *(const vf4*)&x[(size_t)(g * 8 + bx) * (T * II) + (size_t)(t + 1) * II + kx];
    }

    // ---------- productive poll: retry data load until band-valid ----------
    {
      const vf4* mp = (const vf4*)(hx0 + p0 * 32768 + fo);  // mem(t)
      const vf4* hp = (const vf4*)(hx1 + p1 * 32768 + fo);  // h1(t-1)
      vf4 mv, hv;
      for (;;) {
        bypass_ld2x4(mp, hp, mv, hv);
        bool ok = tag_ok(mv.x, tagm) && tag_ok(mv.y, tagm) &&
                  tag_ok(mv.z, tagm) && tag_ok(mv.w, tagm) &&
                  tag_ok(hv.x, tagh) && tag_ok(hv.y, tagh) &&
                  tag_ok(hv.z, tagh) && tag_ok(hv.w, tagh);
        if (__all(ok)) break;
      }
      const vf4 om = {offm, offm, offm, offm};
      const vf4 oh = {offh, offh, offh, offh};
      vf4 mm = mv - om;
      vf4 hh = hv - oh;
      // scatter to LDS (2-way bank aliasing only — free)
      cat0[p1][b0 + 0][256 + js] = mm.x;
      cat0[p1][b0 + 1][256 + js] = mm.y;
      cat0[p1][b0 + 2][256 + js] = mm.z;
      cat0[p1][b0 + 3][256 + js] = mm.w;
      cat1[p0][b0 + 0][js] = (mm.x > 0.5f) ? 1.0f : 0.0f;   // spike recompute
      cat1[p0][b0 + 1][js] = (mm.y > 0.5f) ? 1.0f : 0.0f;
      cat1[p0][b0 + 2][js] = (mm.z > 0.5f) ? 1.0f : 0.0f;
      cat1[p0][b0 + 3][js] = (mm.w > 0.5f) ? 1.0f : 0.0f;
      cat1[p0][b0 + 0][512 + js] = hh.x;
      cat1[p0][b0 + 1][512 + js] = hh.y;
      cat1[p0][b0 + 2][512 + js] = hh.z;
      cat1[p0][b0 + 3][512 + js] = hh.w;
      if (tid < 512) {
        int bx = tid >> 6, kx = (tid & 63) * 4;
        *(vf4*)&cat0[p1][bx][kx] = xv;
      }
    }
    __syncthreads();  // S2 — the ONLY barrier per step

    // ---------- dot1: [s0[t] ; h1[t-1]] @ Wc1 (K=1024), R=1 ----------
#pragma unroll
    for (int b = 0; b < 8; ++b) acc[b] = vf4{0, 0, 0, 0};
    {
      const vf4* wr = Wc1p + (size_t)j * 1024;
#pragma unroll
      for (int ig = 0; ig < 4; ++ig) {
        const int k0 = ig * 256 + kl * 4;
        vf4 w0 = wr[k0], w1 = wr[k0 + 1], w2 = wr[k0 + 2], w3 = wr[k0 + 3];
#pragma unroll
        for (int b = 0; b < 8; ++b) {
          vf4 av = *(const vf4*)&cat1[p0][b][k0];
          acc[b] += av.x * w0; acc[b] += av.y * w1;
          acc[b] += av.z * w2; acc[b] += av.w * w3;
        }
      }
    }

    // ---------- in-wave reduce + finalize layer 1 (registers only) ----------
    {
      vf4 p = reduce8(acc, kl) + bh1p[j];
      float cn  = sigf(p.y) * c1 + sigf(p.x) * tanh_fast(p.z);
      float hn  = sigf(p.w) * tanh_fast(cn);
      float h1n = hn * 0.2f + sp;              // output neuron: h*decay + input(spike)
      c1 = cn;
      if (rep0) {
        // tagged store; written at step t -> consumers at t+1 expect band tagm(t)
        bypass_st(&hx1[p0 * 32768 + g * 4096 + j * 8 + b_loc], h1n + offm);
        out[(size_t)b_glob * (T * HH) + (size_t)t * HH + j] = h1n;
        if (t == T - 1) {
          out[HOFF + 32768 + b_glob * 512 + j] = h1n;
          out[COFF + 32768 + b_glob * 512 + j] = cn;
        }
      }
    }
    // no trailing barrier: next dot0 reads cat0[p1] (fully written pre-S2);
    // any wave's step-t+1 scatter targets cat0[p0]/cat1[p1] — disjoint from
    // all step-t readers. One-barrier loop cannot accumulate iteration skew.
  }
}

// ---------------- launch ----------------
extern "C" void kernel_launch(void* const* d_in, const int* in_sizes, int n_in,
                              void* d_out, int out_size, void* d_ws, size_t ws_size,
                              hipStream_t stream) {
  const float* x   = (const float*)d_in[0];
  const float* Wx0 = (const float*)d_in[1];
  const float* Wh0 = (const float*)d_in[2];
  const float* bh0 = (const float*)d_in[3];
  const float* Wx1 = (const float*)d_in[4];
  const float* Wh1 = (const float*)d_in[5];
  const float* bh1 = (const float*)d_in[6];
  float* out = (float*)d_out;
  float* ws  = (float*)d_ws;

  float* Wc0p  = ws + WS_WC0;
  float* Wc1p  = ws + WS_WC1;
  float* bh0pf = ws + WS_BH0;
  float* bh1pf = ws + WS_BH1;
  float* hx0   = ws + WS_HX0;
  float* hx1   = ws + WS_HX1;

  // zero both hx0 slots + hx1 slot0 (zeros = no valid band); fill hx1 slot1
  // with 0 + tag1 offset (8.0f) so t=0 reads h1(-1)=0 as already-valid.
  hipMemsetAsync(hx0, 0, 2 * 64 * 512 * sizeof(float), stream);
  hipMemsetAsync(hx1, 0, 64 * 512 * sizeof(float), stream);
  hipMemsetAsync(out + SOFF + BB * HH, 0, BB * HH * sizeof(float), stream);

  pack_wc<<<dim3(512), dim3(256), 0, stream>>>(Wx0, Wh0, 256, 768, Wc0p);
  pack_wc<<<dim3(512), dim3(256), 0, stream>>>(Wx1, Wh1, 512, 1024, Wc1p);
  pack_bias<<<dim3(16), dim3(256), 0, stream>>>(bh0, bh1, bh0pf, bh1pf);
  fill_tag<<<dim3(32), dim3(1024), 0, stream>>>(hx1 + 32768, 8.0f);

  aslstm_main<<<dim3(256), dim3(1024), 0, stream>>>(
      (const vf4*)Wc0p, (const vf4*)Wc1p, (const vf4*)bh0pf, (const vf4*)bh1pf,
      x, hx0, hx1, out);
}

// Round 7
// 7460.249 us; speedup vs baseline: 1.1993x; 1.0291x over previous
//
#include <hip/hip_runtime.h>
#include <math.h>

typedef float vf4 __attribute__((ext_vector_type(4)));

// Problem dims (fixed by reference)
constexpr int T  = 512;
constexpr int BB = 64;    // batch
constexpr int II = 256;   // input
constexpr int HH = 512;   // hidden

// d_out layout (floats): out[B,T,H] | s[2,B,H] | h[2,B,H] | c[2,B,H]
constexpr int SOFF = BB * T * HH;          // 16777216
constexpr int HOFF = SOFF + 2 * BB * HH;
constexpr int COFF = HOFF + 2 * BB * HH;

// Workspace layout (float offsets). ~15.3 MB.
constexpr int WS_WC0 = 0;          // [512 j][768 k] vf4  (Wx0;Wh0 stacked)
constexpr int WS_WC1 = 1572864;    // [512 j][1024 k] vf4 (Wx1;Wh1 stacked)
constexpr int WS_BH0 = 3670016;    // [512] vf4
constexpr int WS_BH1 = 3672064;
constexpr int WS_HX0 = 3674112;    // mem exchange: [2 slot][8 g][512 j][8 b] f
constexpr int WS_HX1 = 3739648;    // h1  exchange: same layout

// ---------------- cross-XCD-coherent primitives: DEVICE scope (sc1) ---------
// sc1 = device scope: bypasses the (incoherent) per-XCD L2, MALL-resident.
// r12 lesson: FETCH_SIZE counts TCC<->fabric traffic; MALL hits are behind it.
__device__ __forceinline__ void bypass_st(float* p, float v) {
  asm volatile("global_store_dword %0, %1, off sc1" :: "v"(p), "v"(v) : "memory");
}
// two 16B loads, ONE wait (batched latency); "=&v" early-clobber load-bearing
__device__ __forceinline__ void bypass_ld2x4(const vf4* p0, const vf4* p1, vf4& r0, vf4& r1) {
  asm volatile(
      "global_load_dwordx4 %0, %2, off sc1\n\t"
      "global_load_dwordx4 %1, %3, off sc1\n\t"
      "s_waitcnt vmcnt(0)"
      : "=&v"(r0), "=&v"(r1) : "v"(p0), "v"(p1) : "memory");
}

// ---------------- self-validating tagged exchange ----------------
// Values exchanged are bounded: mem in (-1,1), h1 in (-0.2,1.2). Producer at
// step t stores  v' = v + OFF(t),  OFF(t) = 4 + 4*((t>>1)&1)  -> bands
// (3,5.2) for tag0, (7,9.2) for tag1. A slot is revisited at t+2, whose tag
// always FLIPS, and memset zeros match neither band — so band membership ==
// "this step's value is here". The tag travels IN the same atomic dword as
// the data: no flags, no release drain, no S1 barrier. Decode rounding
// ~1ulp@8.5 per step; observed absmax 0.0083 << 0.0323 threshold (r13).
__device__ __forceinline__ bool tag_ok(float v, bool hi) {
  return hi ? (v > 6.0f) : (v > 2.0f && v < 6.0f);
}

__device__ __forceinline__ float sigf(float x) { return 1.0f / (1.0f + __expf(-x)); }
__device__ __forceinline__ float tanh_fast(float x) {
  return 1.0f - 2.0f / (1.0f + __expf(2.0f * x));
}

__device__ __forceinline__ float sxor(float v, int m) { return __shfl_xor(v, m, 64); }
__device__ __forceinline__ vf4 sxor4(vf4 v, int m) {
  vf4 r; r.x = sxor(v.x, m); r.y = sxor(v.y, m); r.z = sxor(v.z, m); r.w = sxor(v.w, m);
  return r;
}

// 3-bit bit-reversal (self-inverse): lane<->batch map for the split butterfly
__device__ __forceinline__ int rev3(int v) {
  return ((v & 1) << 2) | (v & 2) | ((v >> 2) & 1);
}

// Batch-splitting butterfly: in: acc[8] = partials for batches 0..7 over this
// lane's k-chunk. out: complete wave-sum vf4 for batch rev3(kl&7) (8 replicas).
__device__ __forceinline__ vf4 reduce8(const vf4* acc, int kl) {
  const int sel = kl & 1;
  vf4 n0[4];
#pragma unroll
  for (int i = 0; i < 4; ++i) {
    vf4 snd = sel ? acc[i] : acc[i + 4];
    vf4 kp  = sel ? acc[i + 4] : acc[i];
    n0[i] = kp + sxor4(snd, 1);
  }
  const int sel2 = (kl >> 1) & 1;
  vf4 n1[2];
#pragma unroll
  for (int i = 0; i < 2; ++i) {
    vf4 snd = sel2 ? n0[i] : n0[i + 2];
    vf4 kp  = sel2 ? n0[i + 2] : n0[i];
    n1[i] = kp + sxor4(snd, 2);
  }
  const int sel3 = (kl >> 2) & 1;
  vf4 snd = sel3 ? n1[0] : n1[1];
  vf4 kp  = sel3 ? n1[1] : n1[0];
  vf4 r = kp + sxor4(snd, 4);
  r += sxor4(r, 8);
  r += sxor4(r, 16);
  r += sxor4(r, 32);
  return r;
}

// ---------------- setup kernels ----------------
__global__ void pack_wc(const float* __restrict__ A, const float* __restrict__ B,
                        int Ka, int K, float* __restrict__ Wp) {
  const int j = blockIdx.x;
  for (int k = threadIdx.x; k < K; k += 256) {
    const float* src = (k < Ka) ? (A + (size_t)k * 2048) : (B + (size_t)(k - Ka) * 2048);
    vf4 v = {src[j], src[512 + j], src[1024 + j], src[1536 + j]};
    ((vf4*)Wp)[(size_t)j * K + k] = v;
  }
}

__global__ void pack_bias(const float* __restrict__ bh0, const float* __restrict__ bh1,
                          float* __restrict__ bh0p, float* __restrict__ bh1p) {
  const int i = blockIdx.x * blockDim.x + threadIdx.x;  // 4096
  if (i < 2048) {
    bh0p[i] = bh0[(i & 3) * 512 + (i >> 2)];
  } else {
    int q = i - 2048;
    bh1p[q] = bh1[(q & 3) * 512 + (q >> 2)];
  }
}

// hx1 slot1 must read as "h1(-1)=0 with tag1" at t=0: fill with 0 + 8.0.
__global__ void fill_tag(float* __restrict__ p, float v) {
  p[blockIdx.x * 1024 + threadIdx.x] = v;
}

// ---------------- main persistent kernel ----------------
// Round 14 (= r13 + dot0 weight residency + poll backoff).
//  - Tagged exchange, ONE barrier per step (r13, verified).
//  - NEW: dot0's weights (12 vf4/wave, loop-invariant) hoisted into registers
//    before the t-loop. dot0 becomes pure LDS+FMA — no global loads on the
//    critical inter-block path (S2 -> dot1 -> dot0 -> mem store -> consumers'
//    polls), and the post-barrier L2 burst halves. VGPR 64 -> ~112 (budget:
//    hard 128 cap for a 16-wave block; watch for spill).
//  - NEW: two-tier poll backoff — 4 immediate retries, then s_sleep(1) per
//    retry. Kills the congestion-collapse tail (r13 profiled outlier: one
//    dispatch 36.7ms = 4.2x) without slowing the common fast path.
__global__ __launch_bounds__(1024, 1) void aslstm_main(
    const vf4* __restrict__ Wc0p, const vf4* __restrict__ Wc1p,
    const vf4* __restrict__ bh0p, const vf4* __restrict__ bh1p,
    const float* __restrict__ x,
    float* __restrict__ hx0, float* __restrict__ hx1,
    float* __restrict__ out) {
  const int wg  = blockIdx.x;
  const int xcd = wg & 7;
  const int a   = wg >> 3;
  const int g   = a & 7;
  const int s   = (a >> 3) * 8 + xcd;
  const int tid = threadIdx.x;
  const int jo  = tid >> 6;          // wave -> j column
  const int kl  = tid & 63;          // lane -> k chunk
  const int j   = s * 16 + jo;
  const int b_loc  = rev3(kl & 7);   // batch this lane finalizes (8 replicas)
  const int b_glob = g * 8 + b_loc;
  const bool rep0  = (kl < 8);       // replica 0 does the stores

  __shared__ float cat0[2][8][776];   // [buf][b][ x(256) | h0(512) | pad ]
  __shared__ float cat1[2][8][1032];  // [buf][b][ s0(512) | h1(512) | pad ]

  float c0 = 0.0f, c1 = 0.0f, sp = 0.0f;

  // producer this wave waits on + its load chunk within that producer's region
  const int pl = (jo << 1) | (kl >> 5);   // producer block 0..31 (per lane half)
  const int lc = kl & 31;                 // vf4 chunk 0..31 within producer
  const int js = pl * 16 + (lc >> 1);     // column this chunk carries
  const int b0 = (lc & 1) * 4;            // first batch of the chunk
  const int fo = g * 4096 + pl * 128 + lc * 4;  // float offset in hx[slot]

  // ---- loop-invariant dot0 weights -> registers (12 vf4 = 48 VGPR) ----
  vf4 w0r[3][4];
  {
    const vf4* wr = Wc0p + (size_t)j * 768;
#pragma unroll
    for (int ig = 0; ig < 3; ++ig) {
      const int k0 = ig * 256 + kl * 4;
#pragma unroll
      for (int q = 0; q < 4; ++q) w0r[ig][q] = wr[k0 + q];
    }
  }

  // ---- prologue: stage x(0); h0(-1)=0 directly in LDS buf0 ----
  if (tid < 512) {
    int bx = tid >> 6, kx = (tid & 63) * 4;
    *(vf4*)&cat0[0][bx][kx] = *(const vf4*)&x[(size_t)(g * 8 + bx) * (T * II) + kx];
  }
  {
    int bz = tid >> 7, kz = (tid & 127) * 4;
    *(vf4*)&cat0[0][bz][256 + kz] = vf4{0.0f, 0.0f, 0.0f, 0.0f};
  }
  __syncthreads();

  for (int t = 0; t < T; ++t) {
    const int p0 = t & 1, p1 = p0 ^ 1;
    const bool tagm = ((t >> 1) & 1) != 0;        // band of step-t values
    const bool tagh = (((t + 3) >> 1) & 1) != 0;  // band of step-(t-1) values
    const float offm = tagm ? 8.0f : 4.0f;
    const float offh = tagh ? 8.0f : 4.0f;

    // ---------- dot0: [x_t ; h0[t-1]] @ Wc0 (K=768), weights in regs ----------
    vf4 acc[8];
#pragma unroll
    for (int b = 0; b < 8; ++b) acc[b] = vf4{0, 0, 0, 0};
#pragma unroll
    for (int ig = 0; ig < 3; ++ig) {
      const int k0 = ig * 256 + kl * 4;
#pragma unroll
      for (int b = 0; b < 8; ++b) {
        vf4 av = *(const vf4*)&cat0[p0][b][k0];
        acc[b] += av.x * w0r[ig][0]; acc[b] += av.y * w0r[ig][1];
        acc[b] += av.z * w0r[ig][2]; acc[b] += av.w * w0r[ig][3];
      }
    }

    // ---------- in-wave reduce + finalize layer 0 (registers only) ----------
    {
      vf4 p = reduce8(acc, kl) + bh0p[j];
      float cn  = sigf(p.y) * c0 + sigf(p.x) * tanh_fast(p.z);
      float mem = sigf(p.w) * tanh_fast(cn);   // s*0.2*(1-s) == 0 for s in {0,1}
      float sn  = (mem > 0.5f) ? 1.0f : 0.0f;
      c0 = cn; sp = sn;
      if (rep0) {
        // tagged store: value + band offset, one coalesced 32B packet per wave
        bypass_st(&hx0[p0 * 32768 + g * 4096 + j * 8 + b_loc], mem + offm);
        if (t == T - 1) {
          out[SOFF + b_glob * 512 + j] = sn;
          out[HOFF + b_glob * 512 + j] = mem;
          out[COFF + b_glob * 512 + j] = cn;
        }
      }
    }

    // x(t+1) prefetch into regs (plain cached load)
    vf4 xv = vf4{0, 0, 0, 0};
    if (tid < 512 && t < T - 1) {
      int bx = tid >> 6, kx = (tid & 63) * 4;
      xv = *(const vf4*)&x[(size_t)(g * 8 + bx) * (T * II) + (size_t)(t + 1) * II + kx];
    }

    // ---------- productive poll: retry data load until band-valid ----------
    {
      const vf4* mp = (const vf4*)(hx0 + p0 * 32768 + fo);  // mem(t)
      const vf4* hp = (const vf4*)(hx1 + p1 * 32768 + fo);  // h1(t-1)
      vf4 mv, hv;
      int tries = 0;
      for (;;) {
        bypass_ld2x4(mp, hp, mv, hv);
        bool ok = tag_ok(mv.x, tagm) && tag_ok(mv.y, tagm) &&
                  tag_ok(mv.z, tagm) && tag_ok(mv.w, tagm) &&
                  tag_ok(hv.x, tagh) && tag_ok(hv.y, tagh) &&
                  tag_ok(hv.z, tagh) && tag_ok(hv.w, tagh);
        if (__all(ok)) break;
        // two-tier backoff: fast retries first, then sleep to keep the
        // fabric clear for the laggard producer's stores (r13 outlier fix)
        if (++tries > 4) __builtin_amdgcn_s_sleep(1);
      }
      const vf4 om = {offm, offm, offm, offm};
      const vf4 oh = {offh, offh, offh, offh};
      vf4 mm = mv - om;
      vf4 hh = hv - oh;
      // scatter to LDS (2-way bank aliasing only — free)
      cat0[p1][b0 + 0][256 + js] = mm.x;
      cat0[p1][b0 + 1][256 + js] = mm.y;
      cat0[p1][b0 + 2][256 + js] = mm.z;
      cat0[p1][b0 + 3][256 + js] = mm.w;
      cat1[p0][b0 + 0][js] = (mm.x > 0.5f) ? 1.0f : 0.0f;   // spike recompute
      cat1[p0][b0 + 1][js] = (mm.y > 0.5f) ? 1.0f : 0.0f;
      cat1[p0][b0 + 2][js] = (mm.z > 0.5f) ? 1.0f : 0.0f;
      cat1[p0][b0 + 3][js] = (mm.w > 0.5f) ? 1.0f : 0.0f;
      cat1[p0][b0 + 0][512 + js] = hh.x;
      cat1[p0][b0 + 1][512 + js] = hh.y;
      cat1[p0][b0 + 2][512 + js] = hh.z;
      cat1[p0][b0 + 3][512 + js] = hh.w;
      if (tid < 512) {
        int bx = tid >> 6, kx = (tid & 63) * 4;
        *(vf4*)&cat0[p1][bx][kx] = xv;
      }
    }
    __syncthreads();  // S2 — the ONLY barrier per step

    // ---------- dot1: [s0[t] ; h1[t-1]] @ Wc1 (K=1024), streamed weights ----------
#pragma unroll
    for (int b = 0; b < 8; ++b) acc[b] = vf4{0, 0, 0, 0};
    {
      const vf4* wr = Wc1p + (size_t)j * 1024;
#pragma unroll
      for (int ig = 0; ig < 4; ++ig) {
        const int k0 = ig * 256 + kl * 4;
        vf4 w0 = wr[k0], w1 = wr[k0 + 1], w2 = wr[k0 + 2], w3 = wr[k0 + 3];
#pragma unroll
        for (int b = 0; b < 8; ++b) {
          vf4 av = *(const vf4*)&cat1[p0][b][k0];
          acc[b] += av.x * w0; acc[b] += av.y * w1;
          acc[b] += av.z * w2; acc[b] += av.w * w3;
        }
      }
    }

    // ---------- in-wave reduce + finalize layer 1 (registers only) ----------
    {
      vf4 p = reduce8(acc, kl) + bh1p[j];
      float cn  = sigf(p.y) * c1 + sigf(p.x) * tanh_fast(p.z);
      float hn  = sigf(p.w) * tanh_fast(cn);
      float h1n = hn * 0.2f + sp;              // output neuron: h*decay + input(spike)
      c1 = cn;
      if (rep0) {
        // tagged store; written at step t -> consumers at t+1 expect band tagm(t)
        bypass_st(&hx1[p0 * 32768 + g * 4096 + j * 8 + b_loc], h1n + offm);
        out[(size_t)b_glob * (T * HH) + (size_t)t * HH + j] = h1n;
        if (t == T - 1) {
          out[HOFF + 32768 + b_glob * 512 + j] = h1n;
          out[COFF + 32768 + b_glob * 512 + j] = cn;
        }
      }
    }
    // no trailing barrier: next dot0 reads cat0[p1] (fully written pre-S2);
    // any wave's step-t+1 scatter targets cat0[p0]/cat1[p1] — disjoint from
    // all step-t readers. One-barrier loop cannot accumulate iteration skew.
  }
}

// ---------------- launch ----------------
extern "C" void kernel_launch(void* const* d_in, const int* in_sizes, int n_in,
                              void* d_out, int out_size, void* d_ws, size_t ws_size,
                              hipStream_t stream) {
  const float* x   = (const float*)d_in[0];
  const float* Wx0 = (const float*)d_in[1];
  const float* Wh0 = (const float*)d_in[2];
  const float* bh0 = (const float*)d_in[3];
  const float* Wx1 = (const float*)d_in[4];
  const float* Wh1 = (const float*)d_in[5];
  const float* bh1 = (const float*)d_in[6];
  float* out = (float*)d_out;
  float* ws  = (float*)d_ws;

  float* Wc0p  = ws + WS_WC0;
  float* Wc1p  = ws + WS_WC1;
  float* bh0pf = ws + WS_BH0;
  float* bh1pf = ws + WS_BH1;
  float* hx0   = ws + WS_HX0;
  float* hx1   = ws + WS_HX1;

  // zero both hx0 slots + hx1 slot0 (zeros = no valid band); fill hx1 slot1
  // with 0 + tag1 offset (8.0f) so t=0 reads h1(-1)=0 as already-valid.
  hipMemsetAsync(hx0, 0, 2 * 64 * 512 * sizeof(float), stream);
  hipMemsetAsync(hx1, 0, 64 * 512 * sizeof(float), stream);
  hipMemsetAsync(out + SOFF + BB * HH, 0, BB * HH * sizeof(float), stream);

  pack_wc<<<dim3(512), dim3(256), 0, stream>>>(Wx0, Wh0, 256, 768, Wc0p);
  pack_wc<<<dim3(512), dim3(256), 0, stream>>>(Wx1, Wh1, 512, 1024, Wc1p);
  pack_bias<<<dim3(16), dim3(256), 0, stream>>>(bh0, bh1, bh0pf, bh1pf);
  fill_tag<<<dim3(32), dim3(1024), 0, stream>>>(hx1 + 32768, 8.0f);

  aslstm_main<<<dim3(256), dim3(1024), 0, stream>>>(
      (const vf4*)Wc0p, (const vf4*)Wc1p, (const vf4*)bh0pf, (const vf4*)bh1pf,
      x, hx0, hx1, out);
}